// Round 16
// baseline (488.890 us; speedup 1.0000x reference)
//
#include <hip/hip_runtime.h>
#include <hip/hip_bf16.h>

// B=4, T=2048, C=1024, D=64 ; causal single-head attention, fp32 in/out.
// ONE kernel, 512 blocks x 512 threads, all co-resident (flag protocol):
//  phase 0: blocks 0..47 convert weights -> bf16 transposed wt  (flag)
//  phase A: 6 waves/block project Q/K/V for the block's 16 rows (flag)
//  phase B: 8-wave KV-split flash attention (r15 swapped-softmax body)
constexpr int Bn = 4;
constexpr int Tn = 2048;
constexpr int Cn = 1024;
constexpr int Dn = 64;
constexpr unsigned MAGIC = 0x5EEDF00Du;   // != 0xAAAAAAAA poison

typedef __attribute__((ext_vector_type(8))) short short8;  // 8 bf16
typedef __attribute__((ext_vector_type(4))) float f32x4;   // MFMA acc

__device__ inline short f2bf(float f) {
    unsigned u = __builtin_bit_cast(unsigned, f);
    u += 0x7FFFu + ((u >> 16) & 1u);
    return (short)(u >> 16);
}

// ---------------------------------------------------------------------------
// launch_bounds(512,4): >=4 waves/SIMD => 2 blocks/CU x 256 CU = 512 resident
// (LDS 54.3KB x 2 <= 160KB) => flag waits cannot deadlock.
// Fragment convention (consistent A/B => k-permutation cancels):
//   A slot(lane,j)=A[lane&15][8*(lane>>4)+j], B slot=B[8*(lane>>4)+j][lane&15]
//   C/D (verified): row=(lane>>4)*4+reg, col=lane&15
// ---------------------------------------------------------------------------
__global__ __launch_bounds__(512, 4) void fused_all(
    const float* __restrict__ x,
    const float* __restrict__ wq, const float* __restrict__ wk,
    const float* __restrict__ wv,
    const float* __restrict__ bq, const float* __restrict__ bk,
    const float* __restrict__ bv,
    short* __restrict__ wt,
    short* __restrict__ Qbf, short* __restrict__ Kbf, short* __restrict__ Vt,
    unsigned* __restrict__ pflags, unsigned* __restrict__ qflags,
    float* __restrict__ out)
{
    __shared__ __align__(16) short Plds[8][16][72];
    __shared__ float o_part[8][16][68];
    __shared__ float ml_part[8][2][16];

    const int tid = threadIdx.x;
    const int w = tid >> 6, l = tid & 63;
    const int i = l & 15, g = l >> 4;
    const int bid = blockIdx.x;                   // 0..511
    const int rowbase = bid * 16;                 // global row (b*Tn + t)
    const int b = rowbase >> 11;                  // batch
    const int qw = rowbase & (Tn - 1);            // q-tile start within batch

    // ============ PHASE 0: weights -> bf16 transposed (blocks 0..47) ========
    if (bid < 48) {
        const int sel = bid >> 4;                 // 3 sels x 16 parts
        const float* wsrc = sel == 0 ? wq : (sel == 1 ? wk : wv);
        short* o = wt + (size_t)sel * Dn * Cn;
        const int base = (bid & 15) * 4096;
        for (int idx = base + tid; idx < base + 4096; idx += 512) {
            int n = idx >> 10, k = idx & 1023;    // write o[n][k] coalesced
            o[idx] = f2bf(wsrc[k * Dn + n]);
        }
    }
    __threadfence();
    __syncthreads();
    if (bid < 48 && tid == 0) atomicExch(&pflags[bid], MAGIC);

    // wait for all wt slices
    if (w == 0 && l < 48)
        while (atomicAdd(&pflags[l], 0u) != MAGIC) __builtin_amdgcn_s_sleep(16);
    __syncthreads();
    __threadfence();

    // ============ PHASE A: QKV projection (waves 0..5) ======================
    if (w < 6) {
        const int sel = w >> 1, nh = w & 1;       // sel 0..2, col-half
        const short* ws   = wt + (size_t)sel * Dn * Cn;
        const float* bias = sel == 0 ? bq : (sel == 1 ? bk : bv);

        f32x4 acc[2];
        #pragma unroll
        for (int t2 = 0; t2 < 2; ++t2)
            #pragma unroll
            for (int r = 0; r < 4; ++r) acc[t2][r] = 0.f;

        const float* xrow = x + (size_t)(rowbase + i) * Cn + 8 * g;
        const short* wb0  = ws + (size_t)(nh * 32 + i) * Cn + 8 * g;
        const short* wb1  = wb0 + (size_t)16 * Cn;

        for (int k0 = 0; k0 < Cn; k0 += 32) {
            float4 x0 = *reinterpret_cast<const float4*>(xrow + k0);
            float4 x1 = *reinterpret_cast<const float4*>(xrow + k0 + 4);
            short8 af;
            af[0] = f2bf(x0.x); af[1] = f2bf(x0.y); af[2] = f2bf(x0.z); af[3] = f2bf(x0.w);
            af[4] = f2bf(x1.x); af[5] = f2bf(x1.y); af[6] = f2bf(x1.z); af[7] = f2bf(x1.w);
            short8 b0 = *reinterpret_cast<const short8*>(wb0 + k0);
            short8 b1 = *reinterpret_cast<const short8*>(wb1 + k0);
            acc[0] = __builtin_amdgcn_mfma_f32_16x16x32_bf16(af, b0, acc[0], 0, 0, 0);
            acc[1] = __builtin_amdgcn_mfma_f32_16x16x32_bf16(af, b1, acc[1], 0, 0, 0);
        }

        #pragma unroll
        for (int r = 0; r < 4; ++r) {
            const int rho = rowbase + 4 * g + r;          // C/D row (global)
            const int bb = rho >> 11, t = rho & (Tn - 1);
            #pragma unroll
            for (int t2 = 0; t2 < 2; ++t2) {
                const int n = nh * 32 + t2 * 16 + i;      // C/D col
                const float val = acc[t2][r] + bias[n];
                if (sel == 0)      Qbf[(size_t)rho * Dn + n] = f2bf(val * 0.125f);
                else if (sel == 1) Kbf[(size_t)rho * Dn + n] = f2bf(val);
                else               Vt[((size_t)bb * Dn + n) * Tn + t] = f2bf(val);
            }
        }
    }

    // release own 16 rows of Q/K/V
    __threadfence();
    __syncthreads();
    if (tid == 0) atomicExch(&qflags[bid], MAGIC);

    // acquire same-batch producer blocks [b*128 .. bid]
    if (w == 0) {
        for (int j = b * 128 + l; j <= bid; j += 64)
            while (atomicAdd(&qflags[j], 0u) != MAGIC)
                __builtin_amdgcn_s_sleep(16);
    }
    __syncthreads();
    __threadfence();

    // ============ PHASE B: flash attention (r15 body, all 8 waves) ==========
    const short* Qb = Qbf + (size_t)b * Tn * Dn;
    const short* Kb = Kbf + (size_t)b * Tn * Dn;
    const short* Vb = Vt + (size_t)b * Dn * Tn;

    short8 qf0 = *reinterpret_cast<const short8*>(Qb + (size_t)(qw + i) * Dn + 8 * g);
    short8 qf1 = *reinterpret_cast<const short8*>(Qb + (size_t)(qw + i) * Dn + 32 + 8 * g);

    f32x4 o4[4];
    float m = -1e30f, lsum = 0.f;          // per-lane scalars: q-row = i
    #pragma unroll
    for (int dt = 0; dt < 4; ++dt)
        #pragma unroll
        for (int r = 0; r < 4; ++r) o4[dt][r] = 0.f;

    const int nch = (qw + 79) >> 6;
    for (int kb = w; kb < nch; kb += 8) {
        const int K0 = kb * 64;

        // ---- S^T = K Q^T : D[row=key(4g+r), col=q(i)] ----
        f32x4 s[4];
        #pragma unroll
        for (int nt = 0; nt < 4; ++nt)
            #pragma unroll
            for (int r = 0; r < 4; ++r) s[nt][r] = 0.f;
        #pragma unroll
        for (int nt = 0; nt < 4; ++nt) {
            const short* kr = Kb + (size_t)(K0 + nt * 16 + i) * Dn + 8 * g;
            short8 kf0 = *reinterpret_cast<const short8*>(kr);
            short8 kf1 = *reinterpret_cast<const short8*>(kr + 32);
            s[nt] = __builtin_amdgcn_mfma_f32_16x16x32_bf16(kf0, qf0, s[nt], 0, 0, 0);
            s[nt] = __builtin_amdgcn_mfma_f32_16x16x32_bf16(kf1, qf1, s[nt], 0, 0, 0);
        }

        // ---- V-load hoist ----
        short8 vf0[4], vf1[4];
        #pragma unroll
        for (int dt = 0; dt < 4; ++dt) {
            const short* vr = Vb + (size_t)(dt * 16 + i) * Tn + K0 + 8 * g;
            vf0[dt] = *reinterpret_cast<const short8*>(vr);
            vf1[dt] = *reinterpret_cast<const short8*>(vr + 32);
        }

        // ---- causal mask: key = K0+nt*16+4g+r, q = qw+i ----
        if (K0 + 63 > qw) {
            #pragma unroll
            for (int nt = 0; nt < 4; ++nt)
                #pragma unroll
                for (int r = 0; r < 4; ++r)
                    if (K0 + nt * 16 + 4 * g + r > qw + i) s[nt][r] = -1e30f;
        }

        // ---- online softmax (in-lane over 16 keys + 2 shfl rounds) ----
        float rm = s[0][0];
        #pragma unroll
        for (int nt = 0; nt < 4; ++nt)
            #pragma unroll
            for (int r = 0; r < 4; ++r) rm = fmaxf(rm, s[nt][r]);
        rm = fmaxf(rm, __shfl_xor(rm, 16));
        rm = fmaxf(rm, __shfl_xor(rm, 32));

        const float mn = fmaxf(m, rm);
        const float scl = __expf(m - mn);
        m = mn;
        lsum *= scl;

        float sclq[4];
        #pragma unroll
        for (int r = 0; r < 4; ++r) sclq[r] = __shfl(scl, 4 * g + r);
        #pragma unroll
        for (int dt = 0; dt < 4; ++dt)
            #pragma unroll
            for (int r = 0; r < 4; ++r) o4[dt][r] *= sclq[r];

        // ---- P = exp(S-m), row sums in-lane, spill to LDS[q][key] ----
        float rs = 0.f;
        #pragma unroll
        for (int nt = 0; nt < 4; ++nt)
            #pragma unroll
            for (int r = 0; r < 4; ++r) {
                float p = __expf(s[nt][r] - m);
                rs += p;
                Plds[w][i][nt * 16 + 4 * g + r] = f2bf(p);
            }
        rs += __shfl_xor(rs, 16);
        rs += __shfl_xor(rs, 32);
        lsum += rs;

        asm volatile("s_waitcnt lgkmcnt(0)" ::: "memory");
        __builtin_amdgcn_sched_barrier(0);

        // ---- O += P V ----
        short8 pf0 = *reinterpret_cast<const short8*>(&Plds[w][i][8 * g]);
        short8 pf1 = *reinterpret_cast<const short8*>(&Plds[w][i][32 + 8 * g]);
        #pragma unroll
        for (int dt = 0; dt < 4; ++dt) {
            o4[dt] = __builtin_amdgcn_mfma_f32_16x16x32_bf16(pf0, vf0[dt], o4[dt], 0, 0, 0);
            o4[dt] = __builtin_amdgcn_mfma_f32_16x16x32_bf16(pf1, vf1[dt], o4[dt], 0, 0, 0);
        }
    }

    // ---- publish partials ----
    #pragma unroll
    for (int dt = 0; dt < 4; ++dt)
        #pragma unroll
        for (int r = 0; r < 4; ++r)
            o_part[w][4 * g + r][dt * 16 + i] = o4[dt][r];
    if (g == 0) {                          // lanes 0..15: q-row = i
        ml_part[w][0][i] = m;
        ml_part[w][1][i] = lsum;
    }
    __syncthreads();

    // ---- merge: waves 0-3 own output cols [16w, 16w+16) ----
    if (w < 4) {
        #pragma unroll
        for (int r = 0; r < 4; ++r) {
            const int row = 4 * g + r;
            float M = -1e30f;
            #pragma unroll
            for (int p = 0; p < 8; ++p) M = fmaxf(M, ml_part[p][0][row]);
            float L = 0.f, O = 0.f;
            #pragma unroll
            for (int p = 0; p < 8; ++p) {
                float wp = __expf(ml_part[p][0][row] - M);
                L += ml_part[p][1][row] * wp;
                O += o_part[p][row][w * 16 + i] * wp;
            }
            out[((size_t)b * Tn + qw + row) * Dn + w * 16 + i] = O / L;
        }
    }
}

// ---------------------------------------------------------------------------
extern "C" void kernel_launch(void* const* d_in, const int* in_sizes, int n_in,
                              void* d_out, int out_size, void* d_ws, size_t ws_size,
                              hipStream_t stream) {
    const float* x  = (const float*)d_in[0];
    const float* wq = (const float*)d_in[1];
    const float* wk = (const float*)d_in[2];
    const float* wv = (const float*)d_in[3];
    const float* bq = (const float*)d_in[4];
    const float* bk = (const float*)d_in[5];
    const float* bv = (const float*)d_in[6];
    float* out = (float*)d_out;

    short* wt  = (short*)d_ws;                        // 3*64*1024 bf16
    short* Qbf = wt + 3 * Dn * Cn;                    // 4*2048*64 bf16 each
    short* Kbf = Qbf + (size_t)Bn * Tn * Dn;
    short* Vt  = Kbf + (size_t)Bn * Tn * Dn;          // transposed (b,d,t)
    unsigned* pflags = (unsigned*)(Vt + (size_t)Bn * Tn * Dn);  // 48 words
    unsigned* qflags = pflags + 64;                             // 512 words

    fused_all<<<512, 512, 0, stream>>>(
        x, wq, wk, wv, bq, bk, bv, wt, Qbf, Kbf, Vt, pflags, qflags, out);
}